// Round 1
// baseline (967.371 us; speedup 1.0000x reference)
//
#include <hip/hip_runtime.h>

// ---------------------------------------------------------------------------
// GCN: 2x GCNConv(128->128) + ReLU, FC(128->40), log_softmax
// N=100000 nodes, E=3200000 edges, f32 inputs.
// Strategy:
//   deg/dinv + CSR-by-dst build (histogram, scan, fill)
//   h' = (A @ W) * dinv[row]   -- bf16-split MFMA GEMM, bf16 output
//   x' = relu(dinv[d]*(sum_{src->d} h'[src] + h'[d]) + b)  -- wave/node gather
//   out = log_softmax(x3 @ Wfc + bfc)
// ---------------------------------------------------------------------------

typedef __bf16 bf16x8 __attribute__((ext_vector_type(8)));
typedef float f32x4 __attribute__((ext_vector_type(4)));

__device__ __forceinline__ unsigned short f2bf(float f) {
  unsigned u = __float_as_uint(f);
  u += 0x7fffu + ((u >> 16) & 1u);     // RNE
  return (unsigned short)(u >> 16);
}
__device__ __forceinline__ float bf2f(unsigned short h) {
  return __uint_as_float(((unsigned)h) << 16);
}

// ---------------- CSR build ----------------

__global__ void hist_kernel(const int* __restrict__ dst, int E, int* __restrict__ cnt) {
  int e = blockIdx.x * 256 + threadIdx.x;
  if (e < E) atomicAdd(&cnt[dst[e]], 1);
}

__global__ __launch_bounds__(1024) void scan1_kernel(
    const int* __restrict__ cnt, int* __restrict__ row_start,
    int* __restrict__ bsums, float* __restrict__ dinv, int N) {
  __shared__ int wsum[16];
  int tid = threadIdx.x, lane = tid & 63, wid = tid >> 6;
  int i = blockIdx.x * 1024 + tid;
  int v = (i < N) ? cnt[i] : 0;
  if (i < N) dinv[i] = rsqrtf((float)v + 1.0f);   // deg = in-degree + self loop
  int incl = v;
  #pragma unroll
  for (int off = 1; off < 64; off <<= 1) {
    int t = __shfl_up(incl, off);
    if (lane >= off) incl += t;
  }
  if (lane == 63) wsum[wid] = incl;
  __syncthreads();
  int woff = 0;
  for (int w = 0; w < wid; ++w) woff += wsum[w];
  if (i < N) row_start[i] = woff + incl - v;      // block-local exclusive
  if (tid == 0) {
    int tot = 0;
    for (int w = 0; w < 16; ++w) tot += wsum[w];
    bsums[blockIdx.x] = tot;
  }
}

__global__ void scan2_kernel(const int* __restrict__ bsums, int* __restrict__ boffs,
                             int B, int* __restrict__ row_start, int N, int E) {
  int t = threadIdx.x, lane = t & 63, wid = t >> 6;
  int v = (t < B) ? bsums[t] : 0;
  int incl = v;
  #pragma unroll
  for (int off = 1; off < 64; off <<= 1) {
    int u = __shfl_up(incl, off);
    if (lane >= off) incl += u;
  }
  __shared__ int w0tot;
  if (wid == 0 && lane == 63) w0tot = incl;
  __syncthreads();
  int excl = incl - v + (wid ? w0tot : 0);
  if (t < B) boffs[t] = excl;
  if (t == 0) row_start[N] = E;
}

__global__ __launch_bounds__(1024) void scan3_kernel(
    int* __restrict__ row_start, const int* __restrict__ boffs,
    int* __restrict__ offs, int N) {
  int i = blockIdx.x * 1024 + threadIdx.x;
  if (i < N) {
    int r = row_start[i] + boffs[blockIdx.x];
    row_start[i] = r;
    offs[i] = r;
  }
}

__global__ void fill_kernel(const int* __restrict__ src, const int* __restrict__ dst,
                            int E, int* __restrict__ offs, int* __restrict__ csr) {
  int e = blockIdx.x * 256 + threadIdx.x;
  if (e < E) {
    int d = dst[e];
    int p = atomicAdd(&offs[d], 1);
    csr[p] = src[e];
  }
}

// ---------------- W preprocessing: transpose + bf16 split ----------------
// Wt_hi[n][k], Wt_lo[n][k] (128x128 bf16 each) from W[k][n] f32.
__global__ void prep_w_kernel(const float* __restrict__ W,
                              unsigned short* __restrict__ h,
                              unsigned short* __restrict__ l) {
  int idx = blockIdx.x * 256 + threadIdx.x;   // < 16384
  int k = idx >> 7, n = idx & 127;
  float f = W[idx];
  unsigned short hb = f2bf(f);
  h[n * 128 + k] = hb;
  l[n * 128 + k] = f2bf(f - bf2f(hb));
}

// ---------------- GEMM: out_bf16[N,128] = (A[N,128] @ W[128,128]) * dinv[row]
// ASPLIT=1: A is f32, split into hi+lo (3 MFMA per tile)
// ASPLIT=0: A is bf16  (2 MFMA per tile)
// BM=64, BN=128 (4 waves x 32 cols), BK=64 (2 k-steps). XOR-swizzled LDS.
template <int ASPLIT>
__global__ __launch_bounds__(256) void gemm_kernel(
    const float* __restrict__ Af, const unsigned short* __restrict__ Ab,
    const unsigned short* __restrict__ Wh, const unsigned short* __restrict__ Wl,
    const float* __restrict__ dinv, unsigned short* __restrict__ out, int N) {
  __shared__ __align__(16) unsigned short sAh[64 * 64];
  __shared__ __align__(16) unsigned short sAl[ASPLIT ? 64 * 64 : 8];
  __shared__ __align__(16) unsigned short sWh[128 * 64];
  __shared__ __align__(16) unsigned short sWl[128 * 64];

  const int tid = threadIdx.x;
  const int lane = tid & 63, wid = tid >> 6;
  const int brow = blockIdx.x * 64;
  const int nbase = wid * 32;

  f32x4 acc[4][2];
  #pragma unroll
  for (int m = 0; m < 4; ++m)
    #pragma unroll
    for (int n = 0; n < 2; ++n) acc[m][n] = f32x4{0.f, 0.f, 0.f, 0.f};

  for (int ks = 0; ks < 2; ++ks) {
    const int k0 = ks * 64;
    if (ks) __syncthreads();
    // ---- stage A tile (64 rows x 64 k)
    #pragma unroll
    for (int i = 0; i < 4; ++i) {
      int p = tid + 256 * i;                 // 0..1023
      int row = p >> 4;
      int c4 = (p & 15) << 2;
      int grow = brow + row;
      int sidx = row * 64 + (c4 ^ ((row & 7) << 3));
      if (ASPLIT) {
        float4 v = make_float4(0.f, 0.f, 0.f, 0.f);
        if (grow < N) v = *reinterpret_cast<const float4*>(Af + (size_t)grow * 128 + k0 + c4);
        float fs[4] = {v.x, v.y, v.z, v.w};
        unsigned short hh[4], ll[4];
        #pragma unroll
        for (int j = 0; j < 4; ++j) {
          unsigned short hb = f2bf(fs[j]);
          hh[j] = hb;
          ll[j] = f2bf(fs[j] - bf2f(hb));
        }
        *reinterpret_cast<ushort4*>(&sAh[sidx]) = make_ushort4(hh[0], hh[1], hh[2], hh[3]);
        *reinterpret_cast<ushort4*>(&sAl[sidx]) = make_ushort4(ll[0], ll[1], ll[2], ll[3]);
      } else {
        ushort4 v = make_ushort4(0, 0, 0, 0);
        if (grow < N) v = *reinterpret_cast<const ushort4*>(Ab + (size_t)grow * 128 + k0 + c4);
        *reinterpret_cast<ushort4*>(&sAh[sidx]) = v;
      }
    }
    // ---- stage W tile (128 n-rows x 64 k) from pre-transposed global
    #pragma unroll
    for (int i = 0; i < 8; ++i) {
      int p = tid + 256 * i;                 // 0..2047
      int row = p >> 4;                      // n
      int c4 = (p & 15) << 2;                // k
      int sidx = row * 64 + (c4 ^ ((row & 7) << 3));
      *reinterpret_cast<ushort4*>(&sWh[sidx]) =
          *reinterpret_cast<const ushort4*>(Wh + row * 128 + k0 + c4);
      *reinterpret_cast<ushort4*>(&sWl[sidx]) =
          *reinterpret_cast<const ushort4*>(Wl + row * 128 + k0 + c4);
    }
    __syncthreads();
    // ---- MFMA
    #pragma unroll
    for (int kk = 0; kk < 2; ++kk) {
      const int kof = kk * 32 + ((lane >> 4) << 3);
      bf16x8 ah[4], al[ASPLIT ? 4 : 1], bh[2], bl[2];
      #pragma unroll
      for (int m = 0; m < 4; ++m) {
        int row = m * 16 + (lane & 15);
        int sidx = row * 64 + (kof ^ ((row & 7) << 3));
        ah[m] = *reinterpret_cast<const bf16x8*>(&sAh[sidx]);
        if (ASPLIT) al[m] = *reinterpret_cast<const bf16x8*>(&sAl[sidx]);
      }
      #pragma unroll
      for (int n = 0; n < 2; ++n) {
        int col = nbase + n * 16 + (lane & 15);
        int sidx = col * 64 + (kof ^ ((col & 7) << 3));
        bh[n] = *reinterpret_cast<const bf16x8*>(&sWh[sidx]);
        bl[n] = *reinterpret_cast<const bf16x8*>(&sWl[sidx]);
      }
      #pragma unroll
      for (int m = 0; m < 4; ++m)
        #pragma unroll
        for (int n = 0; n < 2; ++n) {
          acc[m][n] = __builtin_amdgcn_mfma_f32_16x16x32_bf16(ah[m], bh[n], acc[m][n], 0, 0, 0);
          acc[m][n] = __builtin_amdgcn_mfma_f32_16x16x32_bf16(ah[m], bl[n], acc[m][n], 0, 0, 0);
          if (ASPLIT)
            acc[m][n] = __builtin_amdgcn_mfma_f32_16x16x32_bf16(al[m], bh[n], acc[m][n], 0, 0, 0);
        }
    }
  }
  // ---- epilogue: scale by dinv[row], store bf16
  #pragma unroll
  for (int m = 0; m < 4; ++m) {
    #pragma unroll
    for (int r = 0; r < 4; ++r) {
      int lrow = m * 16 + ((lane >> 4) << 2) + r;   // D: row=(lane>>4)*4+reg
      int grow = brow + lrow;
      if (grow < N) {
        float dv = dinv[grow];
        #pragma unroll
        for (int n = 0; n < 2; ++n) {
          int col = nbase + n * 16 + (lane & 15);   // D: col=lane&15
          out[(size_t)grow * 128 + col] = f2bf(acc[m][n][r] * dv);
        }
      }
    }
  }
}

// ---------------- Aggregation: one wave per node ----------------
// out[d] = relu(dinv[d] * (sum_{e:dst=d} h'[src_e] + h'[d]) + bias), bf16 out.
__global__ __launch_bounds__(256) void agg_kernel(
    const unsigned short* __restrict__ hp, const int* __restrict__ rs,
    const int* __restrict__ csr, const float* __restrict__ dinv,
    const float* __restrict__ bias, unsigned short* __restrict__ out, int N) {
  int wid = threadIdx.x >> 6, lane = threadIdx.x & 63;
  int node = blockIdx.x * 4 + wid;
  if (node >= N) return;
  const unsigned* hp32 = reinterpret_cast<const unsigned*>(hp);
  unsigned self = hp32[(size_t)node * 64 + lane];
  float a0 = bf2f((unsigned short)(self & 0xffff));
  float a1 = bf2f((unsigned short)(self >> 16));
  int s = rs[node], e = rs[node + 1];
  for (int base = s; base < e; base += 64) {
    int rem = e - base;
    int nb = rem < 64 ? rem : 64;
    int idx = (lane < rem) ? csr[base + lane] : 0;
    int j = 0;
    for (; j + 4 <= nb; j += 4) {
      int s0 = __shfl(idx, j), s1 = __shfl(idx, j + 1);
      int s2 = __shfl(idx, j + 2), s3 = __shfl(idx, j + 3);
      unsigned v0 = hp32[(size_t)s0 * 64 + lane];
      unsigned v1 = hp32[(size_t)s1 * 64 + lane];
      unsigned v2 = hp32[(size_t)s2 * 64 + lane];
      unsigned v3 = hp32[(size_t)s3 * 64 + lane];
      a0 += bf2f((unsigned short)(v0 & 0xffff)) + bf2f((unsigned short)(v1 & 0xffff))
          + bf2f((unsigned short)(v2 & 0xffff)) + bf2f((unsigned short)(v3 & 0xffff));
      a1 += bf2f((unsigned short)(v0 >> 16)) + bf2f((unsigned short)(v1 >> 16))
          + bf2f((unsigned short)(v2 >> 16)) + bf2f((unsigned short)(v3 >> 16));
    }
    for (; j < nb; ++j) {
      int sj = __shfl(idx, j);
      unsigned v = hp32[(size_t)sj * 64 + lane];
      a0 += bf2f((unsigned short)(v & 0xffff));
      a1 += bf2f((unsigned short)(v >> 16));
    }
  }
  float dv = dinv[node];
  float b0v = bias[lane * 2], b1v = bias[lane * 2 + 1];
  float r0 = fmaxf(a0 * dv + b0v, 0.f);
  float r1 = fmaxf(a1 * dv + b1v, 0.f);
  unsigned pack = (unsigned)f2bf(r0) | ((unsigned)f2bf(r1) << 16);
  reinterpret_cast<unsigned*>(out)[(size_t)node * 64 + lane] = pack;
}

// ---------------- FC(128->40) + log_softmax, one wave per node ----------------
__global__ __launch_bounds__(256) void fc_kernel(
    const unsigned short* __restrict__ x, const float* __restrict__ Wfc,
    const float* __restrict__ bfc, float* __restrict__ out, int N) {
  __shared__ float Wl[128 * 40];
  int tid = threadIdx.x;
  for (int i = tid; i < 5120; i += 256) Wl[i] = Wfc[i];
  __syncthreads();
  int wid = tid >> 6, lane = tid & 63;
  int node = blockIdx.x * 4 + wid;
  if (node >= N) return;
  unsigned v = reinterpret_cast<const unsigned*>(x)[(size_t)node * 64 + lane];
  float xa = bf2f((unsigned short)(v & 0xffff));   // feature 2*lane
  float xb = bf2f((unsigned short)(v >> 16));      // feature 2*lane+1
  int cc = lane < 40 ? lane : 39;
  float logit = bfc[cc];
  #pragma unroll
  for (int t = 0; t < 128; ++t) {
    float srcv = (t & 1) ? xb : xa;
    float xt = __shfl(srcv, t >> 1);
    logit += xt * Wl[t * 40 + cc];
  }
  float m = (lane < 40) ? logit : -1e30f;
  #pragma unroll
  for (int off = 32; off >= 1; off >>= 1) m = fmaxf(m, __shfl_xor(m, off));
  float pexp = (lane < 40) ? __expf(logit - m) : 0.f;
  float ssum = pexp;
  #pragma unroll
  for (int off = 32; off >= 1; off >>= 1) ssum += __shfl_xor(ssum, off);
  if (lane < 40) out[(size_t)node * 40 + lane] = logit - m - __logf(ssum);
}

// ---------------- launch ----------------

extern "C" void kernel_launch(void* const* d_in, const int* in_sizes, int n_in,
                              void* d_out, int out_size, void* d_ws, size_t ws_size,
                              hipStream_t stream) {
  const float* x   = (const float*)d_in[0];
  const float* W1  = (const float*)d_in[1];
  const float* b1  = (const float*)d_in[2];
  const float* W2  = (const float*)d_in[3];
  const float* b2  = (const float*)d_in[4];
  const float* Wfc = (const float*)d_in[5];
  const float* bfc = (const float*)d_in[6];
  const int* ei    = (const int*)d_in[7];
  const int N = in_sizes[0] / 128;
  const int E = in_sizes[7] / 2;
  const int* src = ei;
  const int* dst = ei + E;
  float* out = (float*)d_out;

  char* p = (char*)d_ws;
  auto alloc = [&](size_t bytes) -> char* {
    char* r = p;
    p += (bytes + 255) & ~(size_t)255;
    return r;
  };
  float* dinv      = (float*)alloc((size_t)N * 4);
  int* row_start   = (int*)alloc(((size_t)N + 1) * 4);
  int* cnts        = (int*)alloc((size_t)N * 4);        // reused as fill cursors
  int* csr         = (int*)alloc((size_t)E * 4);
  unsigned short* buf1 = (unsigned short*)alloc((size_t)N * 128 * 2);
  unsigned short* buf2 = (unsigned short*)alloc((size_t)N * 128 * 2);
  unsigned short* wt1h = (unsigned short*)alloc(16384 * 2);
  unsigned short* wt1l = (unsigned short*)alloc(16384 * 2);
  unsigned short* wt2h = (unsigned short*)alloc(16384 * 2);
  unsigned short* wt2l = (unsigned short*)alloc(16384 * 2);
  int* bsums       = (int*)alloc(512);
  int* boffs       = (int*)alloc(512);

  hipMemsetAsync(cnts, 0, (size_t)N * 4, stream);

  const int EB = (E + 255) / 256;
  const int SB = (N + 1023) / 1024;
  const int GB = (N + 63) / 64;
  const int WB = (N + 3) / 4;

  hist_kernel<<<EB, 256, 0, stream>>>(dst, E, cnts);
  scan1_kernel<<<SB, 1024, 0, stream>>>(cnts, row_start, bsums, dinv, N);
  scan2_kernel<<<1, 128, 0, stream>>>(bsums, boffs, SB, row_start, N, E);
  scan3_kernel<<<SB, 1024, 0, stream>>>(row_start, boffs, cnts, N);
  fill_kernel<<<EB, 256, 0, stream>>>(src, dst, E, cnts, csr);

  prep_w_kernel<<<64, 256, 0, stream>>>(W1, wt1h, wt1l);
  prep_w_kernel<<<64, 256, 0, stream>>>(W2, wt2h, wt2l);

  gemm_kernel<1><<<GB, 256, 0, stream>>>(x, nullptr, wt1h, wt1l, dinv, buf1, N);
  agg_kernel<<<WB, 256, 0, stream>>>(buf1, row_start, csr, dinv, b1, buf2, N);
  gemm_kernel<0><<<GB, 256, 0, stream>>>(nullptr, buf2, wt2h, wt2l, dinv, buf1, N);
  agg_kernel<<<WB, 256, 0, stream>>>(buf1, row_start, csr, dinv, b2, buf2, N);
  fc_kernel<<<WB, 256, 0, stream>>>(buf2, Wfc, bfc, out, N);
}

// Round 4
// 688.985 us; speedup vs baseline: 1.4041x; 1.4041x over previous
//
#include <hip/hip_runtime.h>

// ---------------------------------------------------------------------------
// GCN: 2x GCNConv(128->128) + ReLU, FC(128->40), log_softmax
// N=100000 nodes, E=3200000 edges, f32 inputs.
//   Bucketed CSR build (bucket = 256 nodes): LDS hist -> scan -> partition
//     (contiguous per-bucket-per-block writes, ~1.5x amp) -> per-bucket
//     counting sort (scatter confined to 32KB, L2-resident).
//   h' = (A @ W) * dinv[row]   -- bf16-split MFMA GEMM, bf16 output
//   x' = relu(dinv[d]*(sum_{src->d} h'[src] + h'[d]) + b)  -- wave/node gather
//   out = log_softmax(x3 @ Wfc + bfc)
// ---------------------------------------------------------------------------

typedef __bf16 bf16x8 __attribute__((ext_vector_type(8)));
typedef float f32x4 __attribute__((ext_vector_type(4)));

__device__ __forceinline__ unsigned short f2bf(float f) {
  unsigned u = __float_as_uint(f);
  u += 0x7fffu + ((u >> 16) & 1u);     // RNE
  return (unsigned short)(u >> 16);
}
__device__ __forceinline__ float bf2f(unsigned short h) {
  return __uint_as_float(((unsigned)h) << 16);
}

#define NBMAX 1024   // max buckets (N <= 262144)

// ---------------- bucket histogram ----------------
__global__ __launch_bounds__(256) void bhist_kernel(
    const int* __restrict__ dst, int E, int nb, int* __restrict__ bcnt) {
  __shared__ int h[NBMAX];
  int tid = threadIdx.x;
  for (int i = tid; i < nb; i += 256) h[i] = 0;
  __syncthreads();
  for (int e = blockIdx.x * 256 + tid; e < E; e += gridDim.x * 256)
    atomicAdd(&h[((unsigned)dst[e]) >> 8], 1);
  __syncthreads();
  for (int i = tid; i < nb; i += 256) {
    int c = h[i];
    if (c) atomicAdd(&bcnt[i], c);
  }
}

// ---------------- bucket scan (single block) ----------------
__global__ __launch_bounds__(512) void bscan_kernel(
    const int* __restrict__ bcnt, int nb, int* __restrict__ bbase,
    int* __restrict__ bcur, int* __restrict__ row_start, int N, int E) {
  __shared__ int ws[8];
  int t = threadIdx.x, lane = t & 63, wid = t >> 6;
  int v = (t < nb) ? bcnt[t] : 0;
  int incl = v;
  #pragma unroll
  for (int off = 1; off < 64; off <<= 1) {
    int u = __shfl_up(incl, off);
    if (lane >= off) incl += u;
  }
  if (lane == 63) ws[wid] = incl;
  __syncthreads();
  int woff = 0;
  for (int w = 0; w < wid; ++w) woff += ws[w];
  int excl = woff + incl - v;
  if (t < nb) { bbase[t] = excl; bcur[t] = excl; }
  if (t == 0) { bbase[nb] = E; row_start[N] = E; }
}

// ---------------- partition edges into buckets ----------------
// Each block owns a 16K-edge chunk; reserves contiguous per-bucket ranges,
// writes packed (src | dstLocal<<17).
__global__ __launch_bounds__(1024) void part_kernel(
    const int* __restrict__ src, const int* __restrict__ dst, int E, int nb,
    int* __restrict__ bcur, unsigned* __restrict__ pbuf) {
  __shared__ int hcnt[NBMAX];
  __shared__ int hbase[NBMAX];
  int tid = threadIdx.x;
  int start = blockIdx.x * 16384;
  int end = min(start + 16384, E);
  for (int i = tid; i < nb; i += 1024) hcnt[i] = 0;
  __syncthreads();
  for (int e = start + tid; e < end; e += 1024)
    atomicAdd(&hcnt[((unsigned)dst[e]) >> 8], 1);
  __syncthreads();
  for (int i = tid; i < nb; i += 1024) {
    int c = hcnt[i];
    if (c) hbase[i] = atomicAdd(&bcur[i], c);
    hcnt[i] = 0;
  }
  __syncthreads();
  for (int e = start + tid; e < end; e += 1024) {
    int d = dst[e];
    int b = ((unsigned)d) >> 8;
    int r = atomicAdd(&hcnt[b], 1);
    pbuf[hbase[b] + r] = (unsigned)src[e] | (((unsigned)(d & 255)) << 17);
  }
}

// ---------------- per-bucket counting sort -> CSR + deg/dinv/row_start ------
__global__ __launch_bounds__(256) void bsort_kernel(
    const unsigned* __restrict__ pbuf, const int* __restrict__ bbase, int N,
    float* __restrict__ dinv, int* __restrict__ row_start, int* __restrict__ csr) {
  __shared__ int cnt[256];
  __shared__ int base[256];
  __shared__ int wsum[4];
  int b = blockIdx.x;
  int s = bbase[b], e = bbase[b + 1];
  int tid = threadIdx.x, lane = tid & 63, wid = tid >> 6;
  cnt[tid] = 0;
  __syncthreads();
  for (int i = s + tid; i < e; i += 256) atomicAdd(&cnt[pbuf[i] >> 17], 1);
  __syncthreads();
  int v = cnt[tid];
  int incl = v;
  #pragma unroll
  for (int off = 1; off < 64; off <<= 1) {
    int u = __shfl_up(incl, off);
    if (lane >= off) incl += u;
  }
  if (lane == 63) wsum[wid] = incl;
  __syncthreads();
  int woff = 0;
  for (int w = 0; w < wid; ++w) woff += wsum[w];
  int excl = woff + incl - v;
  int node = b * 256 + tid;
  if (node < N) {
    row_start[node] = s + excl;
    dinv[node] = rsqrtf((float)v + 1.0f);   // in-degree + self loop
  }
  base[tid] = s + excl;
  cnt[tid] = 0;
  __syncthreads();
  for (int i = s + tid; i < e; i += 256) {
    unsigned p = pbuf[i];
    int nl = p >> 17;
    int r = atomicAdd(&cnt[nl], 1);
    csr[base[nl] + r] = (int)(p & 0x1ffffu);
  }
}

// ---------------- W preprocessing: transpose + bf16 split ----------------
__global__ void prep_w_kernel(const float* __restrict__ W,
                              unsigned short* __restrict__ h,
                              unsigned short* __restrict__ l) {
  int idx = blockIdx.x * 256 + threadIdx.x;   // < 16384
  int k = idx >> 7, n = idx & 127;
  float f = W[idx];
  unsigned short hb = f2bf(f);
  h[n * 128 + k] = hb;
  l[n * 128 + k] = f2bf(f - bf2f(hb));
}

// ---------------- GEMM: out_bf16[N,128] = (A[N,128] @ W[128,128]) * dinv[row]
template <int ASPLIT>
__global__ __launch_bounds__(256) void gemm_kernel(
    const float* __restrict__ Af, const unsigned short* __restrict__ Ab,
    const unsigned short* __restrict__ Wh, const unsigned short* __restrict__ Wl,
    const float* __restrict__ dinv, unsigned short* __restrict__ out, int N) {
  __shared__ __align__(16) unsigned short sAh[64 * 64];
  __shared__ __align__(16) unsigned short sAl[ASPLIT ? 64 * 64 : 8];
  __shared__ __align__(16) unsigned short sWh[128 * 64];
  __shared__ __align__(16) unsigned short sWl[128 * 64];

  const int tid = threadIdx.x;
  const int lane = tid & 63, wid = tid >> 6;
  const int brow = blockIdx.x * 64;
  const int nbase = wid * 32;

  f32x4 acc[4][2];
  #pragma unroll
  for (int m = 0; m < 4; ++m)
    #pragma unroll
    for (int n = 0; n < 2; ++n) acc[m][n] = f32x4{0.f, 0.f, 0.f, 0.f};

  for (int ks = 0; ks < 2; ++ks) {
    const int k0 = ks * 64;
    if (ks) __syncthreads();
    #pragma unroll
    for (int i = 0; i < 4; ++i) {
      int p = tid + 256 * i;
      int row = p >> 4;
      int c4 = (p & 15) << 2;
      int grow = brow + row;
      int sidx = row * 64 + (c4 ^ ((row & 7) << 3));
      if (ASPLIT) {
        float4 v = make_float4(0.f, 0.f, 0.f, 0.f);
        if (grow < N) v = *reinterpret_cast<const float4*>(Af + (size_t)grow * 128 + k0 + c4);
        float fs[4] = {v.x, v.y, v.z, v.w};
        unsigned short hh[4], ll[4];
        #pragma unroll
        for (int j = 0; j < 4; ++j) {
          unsigned short hb = f2bf(fs[j]);
          hh[j] = hb;
          ll[j] = f2bf(fs[j] - bf2f(hb));
        }
        *reinterpret_cast<ushort4*>(&sAh[sidx]) = make_ushort4(hh[0], hh[1], hh[2], hh[3]);
        *reinterpret_cast<ushort4*>(&sAl[sidx]) = make_ushort4(ll[0], ll[1], ll[2], ll[3]);
      } else {
        ushort4 v = make_ushort4(0, 0, 0, 0);
        if (grow < N) v = *reinterpret_cast<const ushort4*>(Ab + (size_t)grow * 128 + k0 + c4);
        *reinterpret_cast<ushort4*>(&sAh[sidx]) = v;
      }
    }
    #pragma unroll
    for (int i = 0; i < 8; ++i) {
      int p = tid + 256 * i;
      int row = p >> 4;
      int c4 = (p & 15) << 2;
      int sidx = row * 64 + (c4 ^ ((row & 7) << 3));
      *reinterpret_cast<ushort4*>(&sWh[sidx]) =
          *reinterpret_cast<const ushort4*>(Wh + row * 128 + k0 + c4);
      *reinterpret_cast<ushort4*>(&sWl[sidx]) =
          *reinterpret_cast<const ushort4*>(Wl + row * 128 + k0 + c4);
    }
    __syncthreads();
    #pragma unroll
    for (int kk = 0; kk < 2; ++kk) {
      const int kof = kk * 32 + ((lane >> 4) << 3);
      bf16x8 ah[4], al[ASPLIT ? 4 : 1], bh[2], bl[2];
      #pragma unroll
      for (int m = 0; m < 4; ++m) {
        int row = m * 16 + (lane & 15);
        int sidx = row * 64 + (kof ^ ((row & 7) << 3));
        ah[m] = *reinterpret_cast<const bf16x8*>(&sAh[sidx]);
        if (ASPLIT) al[m] = *reinterpret_cast<const bf16x8*>(&sAl[sidx]);
      }
      #pragma unroll
      for (int n = 0; n < 2; ++n) {
        int col = nbase + n * 16 + (lane & 15);
        int sidx = col * 64 + (kof ^ ((col & 7) << 3));
        bh[n] = *reinterpret_cast<const bf16x8*>(&sWh[sidx]);
        bl[n] = *reinterpret_cast<const bf16x8*>(&sWl[sidx]);
      }
      #pragma unroll
      for (int m = 0; m < 4; ++m)
        #pragma unroll
        for (int n = 0; n < 2; ++n) {
          acc[m][n] = __builtin_amdgcn_mfma_f32_16x16x32_bf16(ah[m], bh[n], acc[m][n], 0, 0, 0);
          acc[m][n] = __builtin_amdgcn_mfma_f32_16x16x32_bf16(ah[m], bl[n], acc[m][n], 0, 0, 0);
          if (ASPLIT)
            acc[m][n] = __builtin_amdgcn_mfma_f32_16x16x32_bf16(al[m], bh[n], acc[m][n], 0, 0, 0);
        }
    }
  }
  #pragma unroll
  for (int m = 0; m < 4; ++m) {
    #pragma unroll
    for (int r = 0; r < 4; ++r) {
      int lrow = m * 16 + ((lane >> 4) << 2) + r;
      int grow = brow + lrow;
      if (grow < N) {
        float dv = dinv[grow];
        #pragma unroll
        for (int n = 0; n < 2; ++n) {
          int col = nbase + n * 16 + (lane & 15);
          out[(size_t)grow * 128 + col] = f2bf(acc[m][n][r] * dv);
        }
      }
    }
  }
}

// ---------------- Aggregation: one wave per node ----------------
__global__ __launch_bounds__(256) void agg_kernel(
    const unsigned short* __restrict__ hp, const int* __restrict__ rs,
    const int* __restrict__ csr, const float* __restrict__ dinv,
    const float* __restrict__ bias, unsigned short* __restrict__ out, int N) {
  int wid = threadIdx.x >> 6, lane = threadIdx.x & 63;
  int node = blockIdx.x * 4 + wid;
  if (node >= N) return;
  const unsigned* hp32 = reinterpret_cast<const unsigned*>(hp);
  unsigned self = hp32[(size_t)node * 64 + lane];
  float a0 = bf2f((unsigned short)(self & 0xffff));
  float a1 = bf2f((unsigned short)(self >> 16));
  int s = rs[node], e = rs[node + 1];
  for (int base = s; base < e; base += 64) {
    int rem = e - base;
    int nb = rem < 64 ? rem : 64;
    int idx = (lane < rem) ? csr[base + lane] : 0;
    int j = 0;
    for (; j + 4 <= nb; j += 4) {
      int s0 = __shfl(idx, j), s1 = __shfl(idx, j + 1);
      int s2 = __shfl(idx, j + 2), s3 = __shfl(idx, j + 3);
      unsigned v0 = hp32[(size_t)s0 * 64 + lane];
      unsigned v1 = hp32[(size_t)s1 * 64 + lane];
      unsigned v2 = hp32[(size_t)s2 * 64 + lane];
      unsigned v3 = hp32[(size_t)s3 * 64 + lane];
      a0 += bf2f((unsigned short)(v0 & 0xffff)) + bf2f((unsigned short)(v1 & 0xffff))
          + bf2f((unsigned short)(v2 & 0xffff)) + bf2f((unsigned short)(v3 & 0xffff));
      a1 += bf2f((unsigned short)(v0 >> 16)) + bf2f((unsigned short)(v1 >> 16))
          + bf2f((unsigned short)(v2 >> 16)) + bf2f((unsigned short)(v3 >> 16));
    }
    for (; j < nb; ++j) {
      int sj = __shfl(idx, j);
      unsigned v = hp32[(size_t)sj * 64 + lane];
      a0 += bf2f((unsigned short)(v & 0xffff));
      a1 += bf2f((unsigned short)(v >> 16));
    }
  }
  float dv = dinv[node];
  float b0v = bias[lane * 2], b1v = bias[lane * 2 + 1];
  float r0 = fmaxf(a0 * dv + b0v, 0.f);
  float r1 = fmaxf(a1 * dv + b1v, 0.f);
  unsigned pack = (unsigned)f2bf(r0) | ((unsigned)f2bf(r1) << 16);
  reinterpret_cast<unsigned*>(out)[(size_t)node * 64 + lane] = pack;
}

// ---------------- FC(128->40) + log_softmax, one wave per node ----------------
__global__ __launch_bounds__(256) void fc_kernel(
    const unsigned short* __restrict__ x, const float* __restrict__ Wfc,
    const float* __restrict__ bfc, float* __restrict__ out, int N) {
  __shared__ float Wl[128 * 40];
  int tid = threadIdx.x;
  for (int i = tid; i < 5120; i += 256) Wl[i] = Wfc[i];
  __syncthreads();
  int wid = tid >> 6, lane = tid & 63;
  int node = blockIdx.x * 4 + wid;
  if (node >= N) return;
  unsigned v = reinterpret_cast<const unsigned*>(x)[(size_t)node * 64 + lane];
  float xa = bf2f((unsigned short)(v & 0xffff));
  float xb = bf2f((unsigned short)(v >> 16));
  int cc = lane < 40 ? lane : 39;
  float logit = bfc[cc];
  #pragma unroll
  for (int t = 0; t < 128; ++t) {
    float srcv = (t & 1) ? xb : xa;
    float xt = __shfl(srcv, t >> 1);
    logit += xt * Wl[t * 40 + cc];
  }
  float m = (lane < 40) ? logit : -1e30f;
  #pragma unroll
  for (int off = 32; off >= 1; off >>= 1) m = fmaxf(m, __shfl_xor(m, off));
  float pexp = (lane < 40) ? __expf(logit - m) : 0.f;
  float ssum = pexp;
  #pragma unroll
  for (int off = 32; off >= 1; off >>= 1) ssum += __shfl_xor(ssum, off);
  if (lane < 40) out[(size_t)node * 40 + lane] = logit - m - __logf(ssum);
}

// ---------------- launch ----------------

extern "C" void kernel_launch(void* const* d_in, const int* in_sizes, int n_in,
                              void* d_out, int out_size, void* d_ws, size_t ws_size,
                              hipStream_t stream) {
  const float* x   = (const float*)d_in[0];
  const float* W1  = (const float*)d_in[1];
  const float* b1  = (const float*)d_in[2];
  const float* W2  = (const float*)d_in[3];
  const float* b2  = (const float*)d_in[4];
  const float* Wfc = (const float*)d_in[5];
  const float* bfc = (const float*)d_in[6];
  const int* ei    = (const int*)d_in[7];
  const int N = in_sizes[0] / 128;
  const int E = in_sizes[7] / 2;
  const int* src = ei;
  const int* dst = ei + E;
  float* out = (float*)d_out;

  char* p = (char*)d_ws;
  auto alloc = [&](size_t bytes) -> char* {
    char* r = p;
    p += (bytes + 255) & ~(size_t)255;
    return r;
  };
  float* dinv      = (float*)alloc((size_t)N * 4);
  int* row_start   = (int*)alloc(((size_t)N + 1) * 4);
  int* csr         = (int*)alloc((size_t)E * 4);
  unsigned short* buf1 = (unsigned short*)alloc((size_t)N * 128 * 2);
  unsigned short* buf2 = (unsigned short*)alloc((size_t)N * 128 * 2);
  unsigned short* wt1h = (unsigned short*)alloc(16384 * 2);
  unsigned short* wt1l = (unsigned short*)alloc(16384 * 2);
  unsigned short* wt2h = (unsigned short*)alloc(16384 * 2);
  unsigned short* wt2l = (unsigned short*)alloc(16384 * 2);
  const int NB = (N + 255) >> 8;          // buckets of 256 nodes
  int* bcnt        = (int*)alloc((size_t)NB * 4);
  int* bbase       = (int*)alloc(((size_t)NB + 1) * 4);
  int* bcur        = (int*)alloc((size_t)NB * 4);
  // pbuf aliases buf1: consumed by bsort before gemm1 writes buf1.
  unsigned* pbuf = (unsigned*)buf1;

  hipMemsetAsync(bcnt, 0, (size_t)NB * 4, stream);

  const int PB = (E + 16383) / 16384;
  const int GB = (N + 63) / 64;
  const int WB = (N + 3) / 4;

  bhist_kernel<<<2048, 256, 0, stream>>>(dst, E, NB, bcnt);
  bscan_kernel<<<1, 512, 0, stream>>>(bcnt, NB, bbase, bcur, row_start, N, E);
  part_kernel<<<PB, 1024, 0, stream>>>(src, dst, E, NB, bcur, pbuf);
  bsort_kernel<<<NB, 256, 0, stream>>>(pbuf, bbase, N, dinv, row_start, csr);

  prep_w_kernel<<<64, 256, 0, stream>>>(W1, wt1h, wt1l);
  prep_w_kernel<<<64, 256, 0, stream>>>(W2, wt2h, wt2l);

  gemm_kernel<1><<<GB, 256, 0, stream>>>(x, nullptr, wt1h, wt1l, dinv, buf1, N);
  agg_kernel<<<WB, 256, 0, stream>>>(buf1, row_start, csr, dinv, b1, buf2, N);
  gemm_kernel<0><<<GB, 256, 0, stream>>>(nullptr, buf2, wt2h, wt2l, dinv, buf1, N);
  agg_kernel<<<WB, 256, 0, stream>>>(buf1, row_start, csr, dinv, b2, buf2, N);
  fc_kernel<<<WB, 256, 0, stream>>>(buf2, Wfc, bfc, out, N);
}

// Round 7
// 523.338 us; speedup vs baseline: 1.8485x; 1.3165x over previous
//
#include <hip/hip_runtime.h>

// ---------------------------------------------------------------------------
// GCN: 2x GCNConv(128->128) + ReLU, FC(128->40), log_softmax
// N=100000 nodes, E=3200000 edges, f32 inputs.
//   Bucketed CSR build (bucket = 256 nodes): LDS hist -> scan -> partition
//     -> per-bucket counting sort (scatter confined to 32KB, L2-resident).
//   h' = (A @ W) * dinv[row]   -- bf16-split MFMA GEMM, bf16 output
//   x' = relu(dinv[d]*(sum_{src->d} h'[src] + h'[d]) + b)  -- wave/node gather
//   out = log_softmax(x3 @ Wfc + bfc)  -- MFMA 16x16x32, fused softmax epilogue
// ---------------------------------------------------------------------------

typedef __bf16 bf16x8 __attribute__((ext_vector_type(8)));
typedef float f32x4 __attribute__((ext_vector_type(4)));

__device__ __forceinline__ unsigned short f2bf(float f) {
  unsigned u = __float_as_uint(f);
  u += 0x7fffu + ((u >> 16) & 1u);     // RNE
  return (unsigned short)(u >> 16);
}
__device__ __forceinline__ float bf2f(unsigned short h) {
  return __uint_as_float(((unsigned)h) << 16);
}

#define NBMAX 1024   // max buckets (N <= 262144)

// ---------------- bucket histogram ----------------
__global__ __launch_bounds__(256) void bhist_kernel(
    const int* __restrict__ dst, int E, int nb, int* __restrict__ bcnt) {
  __shared__ int h[NBMAX];
  int tid = threadIdx.x;
  for (int i = tid; i < nb; i += 256) h[i] = 0;
  __syncthreads();
  for (int e = blockIdx.x * 256 + tid; e < E; e += gridDim.x * 256)
    atomicAdd(&h[((unsigned)dst[e]) >> 8], 1);
  __syncthreads();
  for (int i = tid; i < nb; i += 256) {
    int c = h[i];
    if (c) atomicAdd(&bcnt[i], c);
  }
}

// ---------------- bucket scan (single block) ----------------
__global__ __launch_bounds__(512) void bscan_kernel(
    const int* __restrict__ bcnt, int nb, int* __restrict__ bbase,
    int* __restrict__ bcur, int* __restrict__ row_start, int N, int E) {
  __shared__ int ws[8];
  int t = threadIdx.x, lane = t & 63, wid = t >> 6;
  int v = (t < nb) ? bcnt[t] : 0;
  int incl = v;
  #pragma unroll
  for (int off = 1; off < 64; off <<= 1) {
    int u = __shfl_up(incl, off);
    if (lane >= off) incl += u;
  }
  if (lane == 63) ws[wid] = incl;
  __syncthreads();
  int woff = 0;
  for (int w = 0; w < wid; ++w) woff += ws[w];
  int excl = woff + incl - v;
  if (t < nb) { bbase[t] = excl; bcur[t] = excl; }
  if (t == 0) { bbase[nb] = E; row_start[N] = E; }
}

// ---------------- partition edges into buckets ----------------
__global__ __launch_bounds__(1024) void part_kernel(
    const int* __restrict__ src, const int* __restrict__ dst, int E, int nb,
    int* __restrict__ bcur, unsigned* __restrict__ pbuf) {
  __shared__ int hcnt[NBMAX];
  __shared__ int hbase[NBMAX];
  int tid = threadIdx.x;
  int start = blockIdx.x * 16384;
  int end = min(start + 16384, E);
  for (int i = tid; i < nb; i += 1024) hcnt[i] = 0;
  __syncthreads();
  for (int e = start + tid; e < end; e += 1024)
    atomicAdd(&hcnt[((unsigned)dst[e]) >> 8], 1);
  __syncthreads();
  for (int i = tid; i < nb; i += 1024) {
    int c = hcnt[i];
    if (c) hbase[i] = atomicAdd(&bcur[i], c);
    hcnt[i] = 0;
  }
  __syncthreads();
  for (int e = start + tid; e < end; e += 1024) {
    int d = dst[e];
    int b = ((unsigned)d) >> 8;
    int r = atomicAdd(&hcnt[b], 1);
    pbuf[hbase[b] + r] = (unsigned)src[e] | (((unsigned)(d & 255)) << 17);
  }
}

// ---------------- per-bucket counting sort -> CSR + deg/dinv/row_start ------
__global__ __launch_bounds__(256) void bsort_kernel(
    const unsigned* __restrict__ pbuf, const int* __restrict__ bbase, int N,
    float* __restrict__ dinv, int* __restrict__ row_start, int* __restrict__ csr) {
  __shared__ int cnt[256];
  __shared__ int base[256];
  __shared__ int wsum[4];
  int b = blockIdx.x;
  int s = bbase[b], e = bbase[b + 1];
  int tid = threadIdx.x, lane = tid & 63, wid = tid >> 6;
  cnt[tid] = 0;
  __syncthreads();
  for (int i = s + tid; i < e; i += 256) atomicAdd(&cnt[pbuf[i] >> 17], 1);
  __syncthreads();
  int v = cnt[tid];
  int incl = v;
  #pragma unroll
  for (int off = 1; off < 64; off <<= 1) {
    int u = __shfl_up(incl, off);
    if (lane >= off) incl += u;
  }
  if (lane == 63) wsum[wid] = incl;
  __syncthreads();
  int woff = 0;
  for (int w = 0; w < wid; ++w) woff += wsum[w];
  int excl = woff + incl - v;
  int node = b * 256 + tid;
  if (node < N) {
    row_start[node] = s + excl;
    dinv[node] = rsqrtf((float)v + 1.0f);   // in-degree + self loop
  }
  base[tid] = s + excl;
  cnt[tid] = 0;
  __syncthreads();
  for (int i = s + tid; i < e; i += 256) {
    unsigned p = pbuf[i];
    int nl = p >> 17;
    int r = atomicAdd(&cnt[nl], 1);
    csr[base[nl] + r] = (int)(p & 0x1ffffu);
  }
}

// ---------------- W preprocessing: transpose + bf16 split ----------------
__global__ void prep_w_kernel(const float* __restrict__ W,
                              unsigned short* __restrict__ h,
                              unsigned short* __restrict__ l) {
  int idx = blockIdx.x * 256 + threadIdx.x;   // < 16384
  int k = idx >> 7, n = idx & 127;
  float f = W[idx];
  unsigned short hb = f2bf(f);
  h[n * 128 + k] = hb;
  l[n * 128 + k] = f2bf(f - bf2f(hb));
}

// Wfc[128][40] f32 -> Wt_hi/Wt_lo[48][128] bf16, cols 40..47 zero.
__global__ void prep_wfc_kernel(const float* __restrict__ W,
                                unsigned short* __restrict__ h,
                                unsigned short* __restrict__ l) {
  int idx = blockIdx.x * 256 + threadIdx.x;   // < 6144 = 48*128
  if (idx >= 6144) return;
  int n = idx >> 7, k = idx & 127;
  float f = (n < 40) ? W[k * 40 + n] : 0.f;
  unsigned short hb = f2bf(f);
  h[idx] = hb;
  l[idx] = f2bf(f - bf2f(hb));
}

// ---------------- GEMM: out_bf16[N,128] = (A[N,128] @ W[128,128]) * dinv[row]
template <int ASPLIT>
__global__ __launch_bounds__(256) void gemm_kernel(
    const float* __restrict__ Af, const unsigned short* __restrict__ Ab,
    const unsigned short* __restrict__ Wh, const unsigned short* __restrict__ Wl,
    const float* __restrict__ dinv, unsigned short* __restrict__ out, int N) {
  __shared__ __align__(16) unsigned short sAh[64 * 64];
  __shared__ __align__(16) unsigned short sAl[ASPLIT ? 64 * 64 : 8];
  __shared__ __align__(16) unsigned short sWh[128 * 64];
  __shared__ __align__(16) unsigned short sWl[128 * 64];

  const int tid = threadIdx.x;
  const int lane = tid & 63, wid = tid >> 6;
  const int brow = blockIdx.x * 64;
  const int nbase = wid * 32;

  f32x4 acc[4][2];
  #pragma unroll
  for (int m = 0; m < 4; ++m)
    #pragma unroll
    for (int n = 0; n < 2; ++n) acc[m][n] = f32x4{0.f, 0.f, 0.f, 0.f};

  for (int ks = 0; ks < 2; ++ks) {
    const int k0 = ks * 64;
    if (ks) __syncthreads();
    #pragma unroll
    for (int i = 0; i < 4; ++i) {
      int p = tid + 256 * i;
      int row = p >> 4;
      int c4 = (p & 15) << 2;
      int grow = brow + row;
      int sidx = row * 64 + (c4 ^ ((row & 7) << 3));
      if (ASPLIT) {
        float4 v = make_float4(0.f, 0.f, 0.f, 0.f);
        if (grow < N) v = *reinterpret_cast<const float4*>(Af + (size_t)grow * 128 + k0 + c4);
        float fs[4] = {v.x, v.y, v.z, v.w};
        unsigned short hh[4], ll[4];
        #pragma unroll
        for (int j = 0; j < 4; ++j) {
          unsigned short hb = f2bf(fs[j]);
          hh[j] = hb;
          ll[j] = f2bf(fs[j] - bf2f(hb));
        }
        *reinterpret_cast<ushort4*>(&sAh[sidx]) = make_ushort4(hh[0], hh[1], hh[2], hh[3]);
        *reinterpret_cast<ushort4*>(&sAl[sidx]) = make_ushort4(ll[0], ll[1], ll[2], ll[3]);
      } else {
        ushort4 v = make_ushort4(0, 0, 0, 0);
        if (grow < N) v = *reinterpret_cast<const ushort4*>(Ab + (size_t)grow * 128 + k0 + c4);
        *reinterpret_cast<ushort4*>(&sAh[sidx]) = v;
      }
    }
    #pragma unroll
    for (int i = 0; i < 8; ++i) {
      int p = tid + 256 * i;
      int row = p >> 4;
      int c4 = (p & 15) << 2;
      int sidx = row * 64 + (c4 ^ ((row & 7) << 3));
      *reinterpret_cast<ushort4*>(&sWh[sidx]) =
          *reinterpret_cast<const ushort4*>(Wh + row * 128 + k0 + c4);
      *reinterpret_cast<ushort4*>(&sWl[sidx]) =
          *reinterpret_cast<const ushort4*>(Wl + row * 128 + k0 + c4);
    }
    __syncthreads();
    #pragma unroll
    for (int kk = 0; kk < 2; ++kk) {
      const int kof = kk * 32 + ((lane >> 4) << 3);
      bf16x8 ah[4], al[ASPLIT ? 4 : 1], bh[2], bl[2];
      #pragma unroll
      for (int m = 0; m < 4; ++m) {
        int row = m * 16 + (lane & 15);
        int sidx = row * 64 + (kof ^ ((row & 7) << 3));
        ah[m] = *reinterpret_cast<const bf16x8*>(&sAh[sidx]);
        if (ASPLIT) al[m] = *reinterpret_cast<const bf16x8*>(&sAl[sidx]);
      }
      #pragma unroll
      for (int n = 0; n < 2; ++n) {
        int col = nbase + n * 16 + (lane & 15);
        int sidx = col * 64 + (kof ^ ((col & 7) << 3));
        bh[n] = *reinterpret_cast<const bf16x8*>(&sWh[sidx]);
        bl[n] = *reinterpret_cast<const bf16x8*>(&sWl[sidx]);
      }
      #pragma unroll
      for (int m = 0; m < 4; ++m)
        #pragma unroll
        for (int n = 0; n < 2; ++n) {
          acc[m][n] = __builtin_amdgcn_mfma_f32_16x16x32_bf16(ah[m], bh[n], acc[m][n], 0, 0, 0);
          acc[m][n] = __builtin_amdgcn_mfma_f32_16x16x32_bf16(ah[m], bl[n], acc[m][n], 0, 0, 0);
          if (ASPLIT)
            acc[m][n] = __builtin_amdgcn_mfma_f32_16x16x32_bf16(al[m], bh[n], acc[m][n], 0, 0, 0);
        }
    }
  }
  #pragma unroll
  for (int m = 0; m < 4; ++m) {
    #pragma unroll
    for (int r = 0; r < 4; ++r) {
      int lrow = m * 16 + ((lane >> 4) << 2) + r;
      int grow = brow + lrow;
      if (grow < N) {
        float dv = dinv[grow];
        #pragma unroll
        for (int n = 0; n < 2; ++n) {
          int col = nbase + n * 16 + (lane & 15);
          out[(size_t)grow * 128 + col] = f2bf(acc[m][n][r] * dv);
        }
      }
    }
  }
}

// ---------------- Aggregation: one wave per node ----------------
__global__ __launch_bounds__(256) void agg_kernel(
    const unsigned short* __restrict__ hp, const int* __restrict__ rs,
    const int* __restrict__ csr, const float* __restrict__ dinv,
    const float* __restrict__ bias, unsigned short* __restrict__ out, int N) {
  int wid = threadIdx.x >> 6, lane = threadIdx.x & 63;
  int node = blockIdx.x * 4 + wid;
  if (node >= N) return;
  const unsigned* hp32 = reinterpret_cast<const unsigned*>(hp);
  unsigned self = hp32[(size_t)node * 64 + lane];
  float a0 = bf2f((unsigned short)(self & 0xffff));
  float a1 = bf2f((unsigned short)(self >> 16));
  int s = rs[node], e = rs[node + 1];
  for (int base = s; base < e; base += 64) {
    int rem = e - base;
    int nb = rem < 64 ? rem : 64;
    int idx = (lane < rem) ? csr[base + lane] : 0;
    int j = 0;
    for (; j + 4 <= nb; j += 4) {
      int s0 = __shfl(idx, j), s1 = __shfl(idx, j + 1);
      int s2 = __shfl(idx, j + 2), s3 = __shfl(idx, j + 3);
      unsigned v0 = hp32[(size_t)s0 * 64 + lane];
      unsigned v1 = hp32[(size_t)s1 * 64 + lane];
      unsigned v2 = hp32[(size_t)s2 * 64 + lane];
      unsigned v3 = hp32[(size_t)s3 * 64 + lane];
      a0 += bf2f((unsigned short)(v0 & 0xffff)) + bf2f((unsigned short)(v1 & 0xffff))
          + bf2f((unsigned short)(v2 & 0xffff)) + bf2f((unsigned short)(v3 & 0xffff));
      a1 += bf2f((unsigned short)(v0 >> 16)) + bf2f((unsigned short)(v1 >> 16))
          + bf2f((unsigned short)(v2 >> 16)) + bf2f((unsigned short)(v3 >> 16));
    }
    for (; j < nb; ++j) {
      int sj = __shfl(idx, j);
      unsigned v = hp32[(size_t)sj * 64 + lane];
      a0 += bf2f((unsigned short)(v & 0xffff));
      a1 += bf2f((unsigned short)(v >> 16));
    }
  }
  float dv = dinv[node];
  float b0v = bias[lane * 2], b1v = bias[lane * 2 + 1];
  float r0 = fmaxf(a0 * dv + b0v, 0.f);
  float r1 = fmaxf(a1 * dv + b1v, 0.f);
  unsigned pack = (unsigned)f2bf(r0) | ((unsigned)f2bf(r1) << 16);
  reinterpret_cast<unsigned*>(out)[(size_t)node * 64 + lane] = pack;
}

// ---------------- FC(128->40) + log_softmax, MFMA ----------------
// One wave per 16 rows. B = Wfc^T hi/lo [48][128] bf16 (cols 40..47 zero).
__global__ __launch_bounds__(256) void fc_kernel(
    const unsigned short* __restrict__ x, const unsigned short* __restrict__ Wth,
    const unsigned short* __restrict__ Wtl, const float* __restrict__ bfc,
    float* __restrict__ out, int N) {
  const int lane = threadIdx.x & 63, w = threadIdx.x >> 6;
  const int rbase = blockIdx.x * 64 + w * 16;
  const int c = lane & 15, q = lane >> 4;
  f32x4 acc[3];
  #pragma unroll
  for (int n = 0; n < 3; ++n) acc[n] = f32x4{0.f, 0.f, 0.f, 0.f};

  const int arow = min(rbase + c, N - 1);      // A frag: row=lane&15, k=(lane>>4)*8
  const unsigned short* aptr = x + (size_t)arow * 128 + q * 8;
  #pragma unroll
  for (int kt = 0; kt < 4; ++kt) {
    bf16x8 a = *reinterpret_cast<const bf16x8*>(aptr + kt * 32);
    #pragma unroll
    for (int n = 0; n < 3; ++n) {
      const unsigned short* bp = Wth + (size_t)(n * 16 + c) * 128 + kt * 32 + q * 8;
      const unsigned short* lp = Wtl + (size_t)(n * 16 + c) * 128 + kt * 32 + q * 8;
      bf16x8 bh = *reinterpret_cast<const bf16x8*>(bp);
      bf16x8 bl = *reinterpret_cast<const bf16x8*>(lp);
      acc[n] = __builtin_amdgcn_mfma_f32_16x16x32_bf16(a, bh, acc[n], 0, 0, 0);
      acc[n] = __builtin_amdgcn_mfma_f32_16x16x32_bf16(a, bl, acc[n], 0, 0, 0);
    }
  }
  float b0 = bfc[c], b1 = bfc[c + 16], b2 = (c < 8) ? bfc[c + 32] : 0.f;
  #pragma unroll
  for (int r = 0; r < 4; ++r) {
    int row = rbase + q * 4 + r;               // C/D: col=lane&15, row=(lane>>4)*4+r
    float v0 = acc[0][r] + b0;
    float v1 = acc[1][r] + b1;
    float v2 = (c < 8) ? (acc[2][r] + b2) : -1e30f;
    float m = fmaxf(v0, fmaxf(v1, v2));
    #pragma unroll
    for (int off = 8; off >= 1; off >>= 1) m = fmaxf(m, __shfl_xor(m, off));
    float s = __expf(v0 - m) + __expf(v1 - m) + ((c < 8) ? __expf(v2 - m) : 0.f);
    #pragma unroll
    for (int off = 8; off >= 1; off >>= 1) s += __shfl_xor(s, off);
    float lse = m + __logf(s);
    if (row < N) {
      out[(size_t)row * 40 + c] = v0 - lse;
      out[(size_t)row * 40 + c + 16] = v1 - lse;
      if (c < 8) out[(size_t)row * 40 + c + 32] = v2 - lse;
    }
  }
}

// ---------------- launch ----------------

extern "C" void kernel_launch(void* const* d_in, const int* in_sizes, int n_in,
                              void* d_out, int out_size, void* d_ws, size_t ws_size,
                              hipStream_t stream) {
  const float* x   = (const float*)d_in[0];
  const float* W1  = (const float*)d_in[1];
  const float* b1  = (const float*)d_in[2];
  const float* W2  = (const float*)d_in[3];
  const float* b2  = (const float*)d_in[4];
  const float* Wfc = (const float*)d_in[5];
  const float* bfc = (const float*)d_in[6];
  const int* ei    = (const int*)d_in[7];
  const int N = in_sizes[0] / 128;
  const int E = in_sizes[7] / 2;
  const int* src = ei;
  const int* dst = ei + E;
  float* out = (float*)d_out;

  char* p = (char*)d_ws;
  auto alloc = [&](size_t bytes) -> char* {
    char* r = p;
    p += (bytes + 255) & ~(size_t)255;
    return r;
  };
  float* dinv      = (float*)alloc((size_t)N * 4);
  int* row_start   = (int*)alloc(((size_t)N + 1) * 4);
  int* csr         = (int*)alloc((size_t)E * 4);
  unsigned short* buf1 = (unsigned short*)alloc((size_t)N * 128 * 2);
  unsigned short* buf2 = (unsigned short*)alloc((size_t)N * 128 * 2);
  unsigned short* wt1h = (unsigned short*)alloc(16384 * 2);
  unsigned short* wt1l = (unsigned short*)alloc(16384 * 2);
  unsigned short* wt2h = (unsigned short*)alloc(16384 * 2);
  unsigned short* wt2l = (unsigned short*)alloc(16384 * 2);
  unsigned short* wfch = (unsigned short*)alloc(6144 * 2);
  unsigned short* wfcl = (unsigned short*)alloc(6144 * 2);
  const int NB = (N + 255) >> 8;          // buckets of 256 nodes
  int* bcnt        = (int*)alloc((size_t)NB * 4);
  int* bbase       = (int*)alloc(((size_t)NB + 1) * 4);
  int* bcur        = (int*)alloc((size_t)NB * 4);
  // pbuf aliases buf1: consumed by bsort before gemm1 writes buf1.
  unsigned* pbuf = (unsigned*)buf1;

  hipMemsetAsync(bcnt, 0, (size_t)NB * 4, stream);

  const int PB = (E + 16383) / 16384;
  const int GB = (N + 63) / 64;
  const int FB = (N + 63) / 64;
  const int WB = (N + 3) / 4;

  bhist_kernel<<<2048, 256, 0, stream>>>(dst, E, NB, bcnt);
  bscan_kernel<<<1, 512, 0, stream>>>(bcnt, NB, bbase, bcur, row_start, N, E);
  part_kernel<<<PB, 1024, 0, stream>>>(src, dst, E, NB, bcur, pbuf);
  bsort_kernel<<<NB, 256, 0, stream>>>(pbuf, bbase, N, dinv, row_start, csr);

  prep_w_kernel<<<64, 256, 0, stream>>>(W1, wt1h, wt1l);
  prep_w_kernel<<<64, 256, 0, stream>>>(W2, wt2h, wt2l);
  prep_wfc_kernel<<<24, 256, 0, stream>>>(Wfc, wfch, wfcl);

  gemm_kernel<1><<<GB, 256, 0, stream>>>(x, nullptr, wt1h, wt1l, dinv, buf1, N);
  agg_kernel<<<WB, 256, 0, stream>>>(buf1, row_start, csr, dinv, b1, buf2, N);
  gemm_kernel<0><<<GB, 256, 0, stream>>>(nullptr, buf2, wt2h, wt2l, dinv, buf1, N);
  agg_kernel<<<WB, 256, 0, stream>>>(buf1, row_start, csr, dinv, b2, buf2, N);
  fc_kernel<<<FB, 256, 0, stream>>>(buf2, wfch, wfcl, bfc, out, N);
}